// Round 1
// baseline (1536.510 us; speedup 1.0000x reference)
//
#include <hip/hip_runtime.h>
#include <hip/hip_bf16.h>

// GIN conv: out = MLP((1+eps)*x + segment_sum(x[src], dst))
// N_NODES=100000, N_EDGES=1600000, NFEAT=NHID=64, NCLASS=16, all fp32.
//
// Kernel 1: atomic scatter-add aggregation (16 threads/edge, float4 per thread).
// Kernel 2: fused (1+eps)*x+agg -> Linear(64,64)+ReLU -> Linear(64,16), one wave
//           per node, weights in LDS.

#define NFEAT 64
#define NHID 64
#define NCLASS 16

__global__ __launch_bounds__(256) void gin_scatter(
    const float4* __restrict__ x4,   // [n_nodes][16] float4 view of x
    const int* __restrict__ ei,      // [2][n_edges]
    float* __restrict__ agg,         // [n_nodes][64]
    int n_edges)
{
    int tid = blockIdx.x * 256 + threadIdx.x;
    int e = tid >> 4;
    int part = tid & 15;
    if (e >= n_edges) return;
    int src = ei[e];
    int dst = ei[n_edges + e];
    float4 v = x4[src * 16 + part];
    float* a = agg + (size_t)dst * NFEAT + part * 4;
    atomicAdd(a + 0, v.x);
    atomicAdd(a + 1, v.y);
    atomicAdd(a + 2, v.z);
    atomicAdd(a + 3, v.w);
}

__global__ __launch_bounds__(256) void gin_mlp(
    const float* __restrict__ x,     // [n_nodes][64]
    const float* __restrict__ agg,   // [n_nodes][64]
    const float* __restrict__ eps_p, // scalar
    const float* __restrict__ W1,    // [64][64]
    const float* __restrict__ b1,    // [64]
    const float* __restrict__ W2,    // [64][16]
    const float* __restrict__ b2,    // [16]
    float* __restrict__ out,         // [n_nodes][16]
    int n_nodes)
{
    __shared__ float sW1[NFEAT * NHID];       // [k][j] row-major
    __shared__ float sW2[NHID * 17];          // [j][c], padded 16->17 vs bank conflicts
    __shared__ float sb1[NHID];
    __shared__ float sb2[NCLASS];
    __shared__ float sh0[4][NFEAT];           // per-wave input row
    __shared__ float sh1[4][NHID];            // per-wave hidden row

    int tid = threadIdx.x;
    for (int i = tid; i < NFEAT * NHID; i += 256) sW1[i] = W1[i];
    for (int i = tid; i < NHID * NCLASS; i += 256) sW2[(i / NCLASS) * 17 + (i % NCLASS)] = W2[i];
    if (tid < NHID) sb1[tid] = b1[tid];
    if (tid < NCLASS) sb2[tid] = b2[tid];
    __syncthreads();

    float eps1 = 1.0f + eps_p[0];
    int wave = tid >> 6;
    int lane = tid & 63;

    for (int node = blockIdx.x * 4 + wave; node < n_nodes; node += gridDim.x * 4) {
        size_t row = (size_t)node * NFEAT;
        // h0 = (1+eps)*x + agg  (lane = feature index; coalesced)
        float h0 = eps1 * x[row + lane] + agg[row + lane];
        sh0[wave][lane] = h0;
        // wave64 lockstep: ds_write then ds_read in program order within one wave

        // hidden: lane j computes relu(b1[j] + sum_k h0[k]*W1[k][j])
        float s = sb1[lane];
        #pragma unroll
        for (int k = 0; k < NFEAT; ++k) {
            s += sh0[wave][k] * sW1[k * NHID + lane];   // broadcast * 2-way(free)
        }
        float h1 = fmaxf(s, 0.0f);
        sh1[wave][lane] = h1;

        // output: lane = c + 16*q; group q sums j in [16q, 16q+16)
        int c = lane & 15;
        int q = lane >> 4;
        float o = 0.0f;
        #pragma unroll
        for (int jj = 0; jj < 16; ++jj) {
            int j = q * 16 + jj;
            o += sh1[wave][j] * sW2[j * 17 + c];
        }
        o += __shfl_xor(o, 16);
        o += __shfl_xor(o, 32);
        if (lane < NCLASS) out[(size_t)node * NCLASS + lane] = o + sb2[lane];
    }
}

extern "C" void kernel_launch(void* const* d_in, const int* in_sizes, int n_in,
                              void* d_out, int out_size, void* d_ws, size_t ws_size,
                              hipStream_t stream) {
    const float* x   = (const float*)d_in[0];
    const int*   ei  = (const int*)d_in[1];
    const float* eps = (const float*)d_in[2];
    const float* W1  = (const float*)d_in[3];
    const float* b1  = (const float*)d_in[4];
    const float* W2  = (const float*)d_in[5];
    const float* b2  = (const float*)d_in[6];
    float* out = (float*)d_out;

    int n_nodes = in_sizes[0] / NFEAT;
    int n_edges = in_sizes[1] / 2;

    float* agg = (float*)d_ws;
    hipMemsetAsync(agg, 0, (size_t)n_nodes * NFEAT * sizeof(float), stream);

    int sc_threads = n_edges * 16;
    gin_scatter<<<(sc_threads + 255) / 256, 256, 0, stream>>>(
        (const float4*)x, ei, agg, n_edges);

    gin_mlp<<<(n_nodes + 3) / 4, 256, 0, stream>>>(
        x, agg, eps, W1, b1, W2, b2, out, n_nodes);
}

// Round 2
// 538.827 us; speedup vs baseline: 2.8516x; 2.8516x over previous
//
#include <hip/hip_runtime.h>
#include <hip/hip_bf16.h>

// GIN conv: out = MLP((1+eps)*x + segment_sum(x[src], dst))
// N_NODES=100000, N_EDGES=1600000, NFEAT=NHID=64, NCLASS=16, all fp32.
//
// Round 2: replace 102.4M fp32 atomics (atomic-throughput-bound, 1357us) with
// CSR build (1.6M int atomics x2 + scan) + fused gather+MLP (no agg array).

#define NFEAT 64
#define NHID 64
#define NCLASS 16

// ---- kernel 1: degree count ----
__global__ __launch_bounds__(256) void k_degree(
    const int* __restrict__ ei, int* __restrict__ cnt, int n_edges)
{
    int e = blockIdx.x * 256 + threadIdx.x;
    if (e >= n_edges) return;
    int dst = ei[n_edges + e];
    atomicAdd(&cnt[dst], 1);
}

// ---- kernel 2: single-block exclusive scan of cnt[0..n) -> row_ptr, cursor ----
// n = n_nodes+1 (virtual cnt[n_nodes] = 0 so row_ptr[n_nodes] = n_edges)
__global__ __launch_bounds__(1024) void k_scan(
    const int* __restrict__ cnt, int* __restrict__ row_ptr,
    int* __restrict__ cursor, int n_nodes)
{
    __shared__ int s_wsums[16];
    __shared__ int s_carry;
    __shared__ int s_total;
    int tid = threadIdx.x;
    int lane = tid & 63, wid = tid >> 6;
    if (tid == 0) s_carry = 0;
    __syncthreads();

    int n = n_nodes + 1;
    for (int base = 0; base < n; base += 1024) {
        int i = base + tid;
        int v = (i < n_nodes) ? cnt[i] : 0;
        // inclusive scan within wave
        int s = v;
        #pragma unroll
        for (int off = 1; off < 64; off <<= 1) {
            int t = __shfl_up(s, off);
            if (lane >= off) s += t;
        }
        if (lane == 63) s_wsums[wid] = s;
        __syncthreads();
        if (wid == 0 && lane < 16) {
            int w = s_wsums[lane];
            int ws = w;
            #pragma unroll
            for (int off = 1; off < 16; off <<= 1) {
                int t = __shfl_up(ws, off);
                if (lane >= off) ws += t;
            }
            s_wsums[lane] = ws - w;           // exclusive wave offset
            if (lane == 15) s_total = ws;
        }
        __syncthreads();
        int excl = s_carry + s_wsums[wid] + (s - v);
        if (i < n) { row_ptr[i] = excl; cursor[i] = excl; }
        __syncthreads();
        if (tid == 0) s_carry += s_total;
        // next iteration's barriers order this write before any read
    }
}

// ---- kernel 3: CSR fill ----
__global__ __launch_bounds__(256) void k_fill(
    const int* __restrict__ ei, int* __restrict__ cursor,
    int* __restrict__ csr_src, int n_edges)
{
    int e = blockIdx.x * 256 + threadIdx.x;
    if (e >= n_edges) return;
    int src = ei[e];
    int dst = ei[n_edges + e];
    int pos = atomicAdd(&cursor[dst], 1);
    csr_src[pos] = src;
}

// ---- kernel 4: fused gather + MLP, one wave per node ----
__global__ __launch_bounds__(256) void k_gather_mlp(
    const float* __restrict__ x,       // [n][64]
    const int* __restrict__ row_ptr,   // [n+1]
    const int* __restrict__ csr_src,   // [n_edges]
    const float* __restrict__ eps_p,
    const float* __restrict__ W1,      // [64][64]
    const float* __restrict__ b1,
    const float* __restrict__ W2,      // [64][16]
    const float* __restrict__ b2,
    float* __restrict__ out,           // [n][16]
    int n_nodes)
{
    __shared__ float sW1[NFEAT * NHID];   // [k][j]
    __shared__ float sW2[NHID * 17];      // [j][c] padded
    __shared__ float sb1[NHID];
    __shared__ float sb2[NCLASS];
    __shared__ float sh0[4][NFEAT];
    __shared__ float sh1[4][NHID];

    int tid = threadIdx.x;
    for (int i = tid; i < NFEAT * NHID; i += 256) sW1[i] = W1[i];
    for (int i = tid; i < NHID * NCLASS; i += 256) sW2[(i / NCLASS) * 17 + (i % NCLASS)] = W2[i];
    if (tid < NHID) sb1[tid] = b1[tid];
    if (tid < NCLASS) sb2[tid] = b2[tid];
    __syncthreads();

    float eps1 = 1.0f + eps_p[0];
    int wave = tid >> 6;
    int lane = tid & 63;

    for (int node = blockIdx.x * 4 + wave; node < n_nodes; node += gridDim.x * 4) {
        int start = row_ptr[node];
        int end   = row_ptr[node + 1];
        float sum = eps1 * x[(size_t)node * NFEAT + lane];

        for (int e0 = start; e0 < end; e0 += 64) {
            int m = end - e0; if (m > 64) m = 64;
            int se = (lane < m) ? csr_src[e0 + lane] : 0;
            #pragma unroll 4
            for (int j = 0; j < m; ++j) {
                int sj = __shfl(se, j);
                sum += x[(size_t)sj * NFEAT + lane];
            }
        }

        sh0[wave][lane] = sum;     // wave-lockstep LDS, no barrier needed

        float s = sb1[lane];
        #pragma unroll
        for (int k = 0; k < NFEAT; ++k)
            s += sh0[wave][k] * sW1[k * NHID + lane];
        float h1 = fmaxf(s, 0.0f);
        sh1[wave][lane] = h1;

        int c = lane & 15;
        int q = lane >> 4;
        float o = 0.0f;
        #pragma unroll
        for (int jj = 0; jj < 16; ++jj) {
            int j = q * 16 + jj;
            o += sh1[wave][j] * sW2[j * 17 + c];
        }
        o += __shfl_xor(o, 16);
        o += __shfl_xor(o, 32);
        if (lane < NCLASS) out[(size_t)node * NCLASS + lane] = o + sb2[lane];
    }
}

extern "C" void kernel_launch(void* const* d_in, const int* in_sizes, int n_in,
                              void* d_out, int out_size, void* d_ws, size_t ws_size,
                              hipStream_t stream) {
    const float* x   = (const float*)d_in[0];
    const int*   ei  = (const int*)d_in[1];
    const float* eps = (const float*)d_in[2];
    const float* W1  = (const float*)d_in[3];
    const float* b1  = (const float*)d_in[4];
    const float* W2  = (const float*)d_in[5];
    const float* b2  = (const float*)d_in[6];
    float* out = (float*)d_out;

    int n_nodes = in_sizes[0] / NFEAT;
    int n_edges = in_sizes[1] / 2;

    // workspace layout (16B-aligned slots)
    char* ws = (char*)d_ws;
    int* cnt     = (int*)ws;                         // n_nodes
    int* row_ptr = (int*)(ws + 400000);              // n_nodes+1
    int* cursor  = (int*)(ws + 800016);              // n_nodes+1
    int* csr_src = (int*)(ws + 1200032);             // n_edges

    hipMemsetAsync(cnt, 0, (size_t)n_nodes * sizeof(int), stream);

    k_degree<<<(n_edges + 255) / 256, 256, 0, stream>>>(ei, cnt, n_edges);
    k_scan<<<1, 1024, 0, stream>>>(cnt, row_ptr, cursor, n_nodes);
    k_fill<<<(n_edges + 255) / 256, 256, 0, stream>>>(ei, cursor, csr_src, n_edges);
    k_gather_mlp<<<2048, 256, 0, stream>>>(
        x, row_ptr, csr_src, eps, W1, b1, W2, b2, out, n_nodes);
}

// Round 3
// 377.830 us; speedup vs baseline: 4.0667x; 1.4261x over previous
//
#include <hip/hip_runtime.h>
#include <hip/hip_bf16.h>

// GIN conv: out = MLP((1+eps)*x + segment_sum(x[src], dst))
// N_NODES=100000, N_EDGES=1600000, NFEAT=NHID=64, NCLASS=16, fp32.
//
// Round 3: (a) multi-block scan (the single-block scan was ~200us serial),
// (b) gather via float4 + LDS-staged indices (4 rows in flight / load group),
// (c) 1024-thread gather blocks: 16 waves share weights, 32-wave/CU ceiling.

#define NFEAT 64
#define NHID 64
#define NCLASS 16
#define SCAN_CHUNK 1024   // elements per scan block (256 thr x 4)

// ---- kernel 1: degree count ----
__global__ __launch_bounds__(256) void k_degree(
    const int* __restrict__ ei, int* __restrict__ cnt, int n_edges)
{
    int e = blockIdx.x * 256 + threadIdx.x;
    if (e >= n_edges) return;
    atomicAdd(&cnt[ei[n_edges + e]], 1);
}

// ---- scan phase A: per-block sums over chunks of 1024 ----
__global__ __launch_bounds__(256) void k_blocksum(
    const int* __restrict__ cnt, int* __restrict__ bs, int n_nodes)
{
    __shared__ int sw[4];
    int t = threadIdx.x, lane = t & 63, wid = t >> 6;
    int i0 = blockIdx.x * SCAN_CHUNK + t * 4;
    int s = 0;
    #pragma unroll
    for (int j = 0; j < 4; ++j) {
        int i = i0 + j;
        if (i < n_nodes) s += cnt[i];
    }
    #pragma unroll
    for (int off = 1; off < 64; off <<= 1) s += __shfl_xor(s, off);
    if (lane == 0) sw[wid] = s;
    __syncthreads();
    if (t == 0) bs[blockIdx.x] = sw[0] + sw[1] + sw[2] + sw[3];
}

// ---- scan phase B: single small block scans the ~98 block sums ----
__global__ __launch_bounds__(256) void k_scanmid(
    const int* __restrict__ bs, int* __restrict__ bo, int nb)
{
    __shared__ int sw[4];
    int t = threadIdx.x, lane = t & 63, wid = t >> 6;
    int v = (t < nb) ? bs[t] : 0;
    int s = v;
    #pragma unroll
    for (int off = 1; off < 64; off <<= 1) {
        int u = __shfl_up(s, off);
        if (lane >= off) s += u;
    }
    if (lane == 63) sw[wid] = s;
    __syncthreads();
    if (t == 0) { int a = 0; for (int i = 0; i < 4; ++i) { int tmp = sw[i]; sw[i] = a; a += tmp; } }
    __syncthreads();
    if (t < nb) bo[t] = (s - v) + sw[wid];
}

// ---- scan phase C: local exclusive scan + block offset -> row_ptr, cursor ----
__global__ __launch_bounds__(256) void k_scanout(
    const int* __restrict__ cnt, const int* __restrict__ bo,
    int* __restrict__ row_ptr, int* __restrict__ cursor, int n_nodes)
{
    __shared__ int sw[4];
    __shared__ int swo[4];
    int t = threadIdx.x, lane = t & 63, wid = t >> 6;
    int i0 = blockIdx.x * SCAN_CHUNK + t * 4;
    int v[4];
    #pragma unroll
    for (int j = 0; j < 4; ++j) v[j] = (i0 + j < n_nodes) ? cnt[i0 + j] : 0;
    int p1 = v[0], p2 = p1 + v[1], p3 = p2 + v[2], p4 = p3 + v[3];
    int s = p4;
    #pragma unroll
    for (int off = 1; off < 64; off <<= 1) {
        int u = __shfl_up(s, off);
        if (lane >= off) s += u;
    }
    int base = s - p4;          // exclusive within wave
    if (lane == 63) sw[wid] = s;
    __syncthreads();
    if (t == 0) { int a = 0; for (int i = 0; i < 4; ++i) { int tmp = sw[i]; swo[i] = a; a += tmp; } }
    __syncthreads();
    int off0 = bo[blockIdx.x] + swo[wid] + base;
    int e[4] = { off0, off0 + p1, off0 + p2, off0 + p3 };
    int n = n_nodes + 1;
    #pragma unroll
    for (int j = 0; j < 4; ++j) {
        int i = i0 + j;
        if (i < n) { row_ptr[i] = e[j]; cursor[i] = e[j]; }
    }
}

// ---- CSR fill ----
__global__ __launch_bounds__(256) void k_fill(
    const int* __restrict__ ei, int* __restrict__ cursor,
    int* __restrict__ csr_src, int n_edges)
{
    int e = blockIdx.x * 256 + threadIdx.x;
    if (e >= n_edges) return;
    int src = ei[e];
    int dst = ei[n_edges + e];
    int pos = atomicAdd(&cursor[dst], 1);
    csr_src[pos] = src;
}

// ---- fused gather + MLP: wave per node, float4 gather, 16 waves/block ----
__global__ __launch_bounds__(1024) void k_gather_mlp(
    const float4* __restrict__ x4,     // [n][16] float4
    const int* __restrict__ row_ptr,
    const int* __restrict__ csr_src,
    const float* __restrict__ eps_p,
    const float* __restrict__ W1,      // [64][64]
    const float* __restrict__ b1,
    const float* __restrict__ W2,      // [64][16]
    const float* __restrict__ b2,
    float* __restrict__ out,           // [n][16]
    int n_nodes)
{
    __shared__ float sW1[NFEAT * NHID];   // [k][j]
    __shared__ float sW2[NHID * 17];      // [j][c] padded
    __shared__ float sb1[NHID];
    __shared__ float sb2[NCLASS];
    __shared__ float sh0[16][NFEAT];
    __shared__ float sh1[16][NHID];
    __shared__ int   sIdx[16][64];

    int tid = threadIdx.x;
    for (int i = tid; i < NFEAT * NHID; i += 1024) sW1[i] = W1[i];
    for (int i = tid; i < NHID * NCLASS; i += 1024) sW2[(i / NCLASS) * 17 + (i % NCLASS)] = W2[i];
    if (tid < NHID) sb1[tid] = b1[tid];
    if (tid < NCLASS) sb2[tid] = b2[tid];
    __syncthreads();

    float eps1 = 1.0f + eps_p[0];
    int wave = tid >> 6;
    int lane = tid & 63;
    int q = lane >> 4;        // row group 0..3
    int f = lane & 15;        // float4 slot 0..15

    for (int node = blockIdx.x * 16 + wave; node < n_nodes; node += gridDim.x * 16) {
        int start = row_ptr[node];
        int end   = row_ptr[node + 1];
        float4 acc = make_float4(0.f, 0.f, 0.f, 0.f);

        for (int e0 = start; e0 < end; e0 += 64) {
            int m = end - e0; if (m > 64) m = 64;
            if (lane < m) sIdx[wave][lane] = csr_src[e0 + lane];
            int tmax = (m + 3) >> 2;
            #pragma unroll 4
            for (int t = 0; t < tmax; ++t) {
                int r = t * 4 + q;
                if (r < m) {
                    int sj = sIdx[wave][r];
                    float4 v = x4[(size_t)sj * 16 + f];
                    acc.x += v.x; acc.y += v.y; acc.z += v.z; acc.w += v.w;
                }
            }
        }
        // reduce the 4 row-groups (each lane ends with the full sum)
        acc.x += __shfl_xor(acc.x, 16); acc.y += __shfl_xor(acc.y, 16);
        acc.z += __shfl_xor(acc.z, 16); acc.w += __shfl_xor(acc.w, 16);
        acc.x += __shfl_xor(acc.x, 32); acc.y += __shfl_xor(acc.y, 32);
        acc.z += __shfl_xor(acc.z, 32); acc.w += __shfl_xor(acc.w, 32);
        // self term
        float4 xs = x4[(size_t)node * 16 + f];
        acc.x += eps1 * xs.x; acc.y += eps1 * xs.y;
        acc.z += eps1 * xs.z; acc.w += eps1 * xs.w;
        if (q == 0) ((float4*)sh0[wave])[f] = acc;   // wave-lockstep LDS

        // hidden: lane j
        float s = sb1[lane];
        #pragma unroll
        for (int k = 0; k < NFEAT; ++k)
            s += sh0[wave][k] * sW1[k * NHID + lane];
        sh1[wave][lane] = fmaxf(s, 0.0f);

        // out: group q sums j in [16q,16q+16), class c = lane&15
        float o = 0.0f;
        #pragma unroll
        for (int jj = 0; jj < 16; ++jj) {
            int j = q * 16 + jj;
            o += sh1[wave][j] * sW2[j * 17 + f];
        }
        o += __shfl_xor(o, 16);
        o += __shfl_xor(o, 32);
        if (lane < NCLASS) out[(size_t)node * NCLASS + lane] = o + sb2[lane];
    }
}

extern "C" void kernel_launch(void* const* d_in, const int* in_sizes, int n_in,
                              void* d_out, int out_size, void* d_ws, size_t ws_size,
                              hipStream_t stream) {
    const float* x   = (const float*)d_in[0];
    const int*   ei  = (const int*)d_in[1];
    const float* eps = (const float*)d_in[2];
    const float* W1  = (const float*)d_in[3];
    const float* b1  = (const float*)d_in[4];
    const float* W2  = (const float*)d_in[5];
    const float* b2  = (const float*)d_in[6];
    float* out = (float*)d_out;

    int n_nodes = in_sizes[0] / NFEAT;   // 100000
    int n_edges = in_sizes[1] / 2;       // 1600000
    int n = n_nodes + 1;
    int nb = (n + SCAN_CHUNK - 1) / SCAN_CHUNK;   // 98

    char* ws = (char*)d_ws;
    int* cnt     = (int*)ws;                   // n_nodes ints
    int* row_ptr = (int*)(ws + 400128);        // n+1
    int* cursor  = (int*)(ws + 800256);        // n+1
    int* bs      = (int*)(ws + 1200384);       // nb
    int* bo      = (int*)(ws + 1200896);       // nb
    int* csr_src = (int*)(ws + 1201408);       // n_edges

    hipMemsetAsync(cnt, 0, (size_t)n_nodes * sizeof(int), stream);

    k_degree<<<(n_edges + 255) / 256, 256, 0, stream>>>(ei, cnt, n_edges);
    k_blocksum<<<nb, 256, 0, stream>>>(cnt, bs, n_nodes);
    k_scanmid<<<1, 256, 0, stream>>>(bs, bo, nb);
    k_scanout<<<nb, 256, 0, stream>>>(cnt, bo, row_ptr, cursor, n_nodes);
    k_fill<<<(n_edges + 255) / 256, 256, 0, stream>>>(ei, cursor, csr_src, n_edges);
    k_gather_mlp<<<1024, 1024, 0, stream>>>(
        (const float4*)x, row_ptr, csr_src, eps, W1, b1, W2, b2, out, n_nodes);
}

// Round 4
// 217.229 us; speedup vs baseline: 7.0732x; 1.7393x over previous
//
#include <hip/hip_runtime.h>
#include <hip/hip_bf16.h>

// GIN conv: out = MLP((1+eps)*x + segment_sum(x[src], dst))
// N_NODES=100000, N_EDGES=1600000, NFEAT=NHID=64, NCLASS=16, fp32.
//
// Round 4: CSR build via 2-level bucket counting-sort (391 buckets x 256 nodes).
// Eliminates 1.6M global returning atomics (k_fill, 128us) and its 106MB of
// line-granular scattered writes. Per-edge atomics are now LDS-only; global
// returning atomics: ~391/block in partition (77K total).
// Gather+MLP kernel unchanged from R3.

#define NFEAT 64
#define NHID 64
#define NCLASS 16

#define PCAP 6144          // per-bucket capacity (mean 4094, sigma 64 -> 32 sigma margin)
#define MAXBUCK 512        // LDS sizing
#define PT 512             // partition threads
#define PEPT 8             // edges per thread in partition (tile 4096)
#define ST 1024            // sort threads
#define SEPT 6             // ST*SEPT = 6144 = PCAP

// ---- k0: init bucket cursors to region starts ----
__global__ __launch_bounds__(512) void k_init(int* __restrict__ cursor, int nbuck)
{
    int t = threadIdx.x;
    if (t < nbuck) cursor[t] = t * PCAP;
}

// ---- k1: partition edges into buckets by dst>>8, packed (src<<8)|(dst&255) ----
__global__ __launch_bounds__(PT) void k_part(
    const int* __restrict__ ei, int* __restrict__ cursor,
    int* __restrict__ dsts, int n_edges, int nbuck)
{
    __shared__ int lcnt[MAXBUCK];
    __shared__ int sbase[MAXBUCK];
    int tid = threadIdx.x;
    for (int i = tid; i < nbuck; i += PT) lcnt[i] = 0;
    __syncthreads();

    int e0 = blockIdx.x * (PT * PEPT);
    int bk[PEPT], rk[PEPT], pk[PEPT];
    #pragma unroll
    for (int k = 0; k < PEPT; ++k) {
        int e = e0 + k * PT + tid;
        if (e < n_edges) {
            int src = ei[e];
            int dst = ei[n_edges + e];
            int b = dst >> 8;
            bk[k] = b;
            pk[k] = (src << 8) | (dst & 255);
            rk[k] = atomicAdd(&lcnt[b], 1);
        } else bk[k] = -1;
    }
    __syncthreads();
    for (int i = tid; i < nbuck; i += PT)
        sbase[i] = lcnt[i] ? atomicAdd(&cursor[i], lcnt[i]) : 0;
    __syncthreads();
    #pragma unroll
    for (int k = 0; k < PEPT; ++k)
        if (bk[k] >= 0) dsts[sbase[bk[k]] + rk[k]] = pk[k];
}

// ---- k2: scan bucket sizes -> bucket bases (1 block, 512 thr, nbuck<=512) ----
__global__ __launch_bounds__(512) void k_bscan(
    const int* __restrict__ cursor, int* __restrict__ bbase,
    int* __restrict__ row_ptr, int nbuck, int n_edges, int n_nodes)
{
    __shared__ int sw[8];
    int t = threadIdx.x, lane = t & 63, wid = t >> 6;
    int v = (t < nbuck) ? (cursor[t] - t * PCAP) : 0;
    int s = v;
    #pragma unroll
    for (int off = 1; off < 64; off <<= 1) {
        int u = __shfl_up(s, off);
        if (lane >= off) s += u;
    }
    if (lane == 63) sw[wid] = s;
    __syncthreads();
    if (t == 0) { int a = 0; for (int i = 0; i < 8; ++i) { int tmp = sw[i]; sw[i] = a; a += tmp; } }
    __syncthreads();
    if (t < nbuck) bbase[t] = (s - v) + sw[wid];
    if (t == 0) row_ptr[n_nodes] = n_edges;
}

// ---- k3: per-bucket counting sort -> csr_src + row_ptr ----
__global__ __launch_bounds__(ST) void k_bsort(
    const int* __restrict__ dsts, const int* __restrict__ cursor,
    const int* __restrict__ bbase, int* __restrict__ csr_src,
    int* __restrict__ row_ptr, int n_nodes)
{
    __shared__ int cnt[256];
    __shared__ int off[256];
    int b = blockIdx.x;
    int tid = threadIdx.x, lane = tid & 63, wid = tid >> 6;
    int s = cursor[b] - b * PCAP;
    int gin = b * PCAP;
    if (tid < 256) cnt[tid] = 0;
    __syncthreads();

    int dk[SEPT], rk[SEPT], sk[SEPT];
    #pragma unroll
    for (int k = 0; k < SEPT; ++k) {
        int i = k * ST + tid;
        if (i < s) {
            int p = dsts[gin + i];
            int d = p & 255;
            dk[k] = d;
            sk[k] = p >> 8;
            rk[k] = atomicAdd(&cnt[d], 1);
        } else dk[k] = -1;
    }
    __syncthreads();
    // exclusive scan of cnt[0..256) by wave 0 (4 per lane)
    if (wid == 0) {
        int c0 = cnt[lane * 4], c1 = cnt[lane * 4 + 1], c2 = cnt[lane * 4 + 2], c3 = cnt[lane * 4 + 3];
        int p1 = c0, p2 = p1 + c1, p3 = p2 + c2, p4 = p3 + c3;
        int ss = p4;
        #pragma unroll
        for (int o = 1; o < 64; o <<= 1) {
            int u = __shfl_up(ss, o);
            if (lane >= o) ss += u;
        }
        int base = ss - p4;
        off[lane * 4] = base; off[lane * 4 + 1] = base + p1;
        off[lane * 4 + 2] = base + p2; off[lane * 4 + 3] = base + p3;
    }
    __syncthreads();
    int bb = bbase[b];
    #pragma unroll
    for (int k = 0; k < SEPT; ++k)
        if (dk[k] >= 0) csr_src[bb + off[dk[k]] + rk[k]] = sk[k];
    int node = b * 256 + tid;
    if (tid < 256 && node < n_nodes) row_ptr[node] = bb + off[tid];
}

// ---- k4: fused gather + MLP (unchanged from R3) ----
__global__ __launch_bounds__(1024) void k_gather_mlp(
    const float4* __restrict__ x4,
    const int* __restrict__ row_ptr,
    const int* __restrict__ csr_src,
    const float* __restrict__ eps_p,
    const float* __restrict__ W1,
    const float* __restrict__ b1,
    const float* __restrict__ W2,
    const float* __restrict__ b2,
    float* __restrict__ out,
    int n_nodes)
{
    __shared__ float sW1[NFEAT * NHID];
    __shared__ float sW2[NHID * 17];
    __shared__ float sb1[NHID];
    __shared__ float sb2[NCLASS];
    __shared__ float sh0[16][NFEAT];
    __shared__ float sh1[16][NHID];
    __shared__ int   sIdx[16][64];

    int tid = threadIdx.x;
    for (int i = tid; i < NFEAT * NHID; i += 1024) sW1[i] = W1[i];
    for (int i = tid; i < NHID * NCLASS; i += 1024) sW2[(i / NCLASS) * 17 + (i % NCLASS)] = W2[i];
    if (tid < NHID) sb1[tid] = b1[tid];
    if (tid < NCLASS) sb2[tid] = b2[tid];
    __syncthreads();

    float eps1 = 1.0f + eps_p[0];
    int wave = tid >> 6;
    int lane = tid & 63;
    int q = lane >> 4;
    int f = lane & 15;

    for (int node = blockIdx.x * 16 + wave; node < n_nodes; node += gridDim.x * 16) {
        int start = row_ptr[node];
        int end   = row_ptr[node + 1];
        float4 acc = make_float4(0.f, 0.f, 0.f, 0.f);

        for (int e0 = start; e0 < end; e0 += 64) {
            int m = end - e0; if (m > 64) m = 64;
            if (lane < m) sIdx[wave][lane] = csr_src[e0 + lane];
            int tmax = (m + 3) >> 2;
            #pragma unroll 4
            for (int t = 0; t < tmax; ++t) {
                int r = t * 4 + q;
                if (r < m) {
                    int sj = sIdx[wave][r];
                    float4 v = x4[(size_t)sj * 16 + f];
                    acc.x += v.x; acc.y += v.y; acc.z += v.z; acc.w += v.w;
                }
            }
        }
        acc.x += __shfl_xor(acc.x, 16); acc.y += __shfl_xor(acc.y, 16);
        acc.z += __shfl_xor(acc.z, 16); acc.w += __shfl_xor(acc.w, 16);
        acc.x += __shfl_xor(acc.x, 32); acc.y += __shfl_xor(acc.y, 32);
        acc.z += __shfl_xor(acc.z, 32); acc.w += __shfl_xor(acc.w, 32);
        float4 xs = x4[(size_t)node * 16 + f];
        acc.x += eps1 * xs.x; acc.y += eps1 * xs.y;
        acc.z += eps1 * xs.z; acc.w += eps1 * xs.w;
        if (q == 0) ((float4*)sh0[wave])[f] = acc;

        float sacc = sb1[lane];
        #pragma unroll
        for (int k = 0; k < NFEAT; ++k)
            sacc += sh0[wave][k] * sW1[k * NHID + lane];
        sh1[wave][lane] = fmaxf(sacc, 0.0f);

        float o = 0.0f;
        #pragma unroll
        for (int jj = 0; jj < 16; ++jj) {
            int j = q * 16 + jj;
            o += sh1[wave][j] * sW2[j * 17 + f];
        }
        o += __shfl_xor(o, 16);
        o += __shfl_xor(o, 32);
        if (lane < NCLASS) out[(size_t)node * NCLASS + lane] = o + sb2[lane];
    }
}

extern "C" void kernel_launch(void* const* d_in, const int* in_sizes, int n_in,
                              void* d_out, int out_size, void* d_ws, size_t ws_size,
                              hipStream_t stream) {
    const float* x   = (const float*)d_in[0];
    const int*   ei  = (const int*)d_in[1];
    const float* eps = (const float*)d_in[2];
    const float* W1  = (const float*)d_in[3];
    const float* b1  = (const float*)d_in[4];
    const float* W2  = (const float*)d_in[5];
    const float* b2  = (const float*)d_in[6];
    float* out = (float*)d_out;

    int n_nodes = in_sizes[0] / NFEAT;            // 100000
    int n_edges = in_sizes[1] / 2;                // 1600000
    int nbuck = (n_nodes + 255) / 256;            // 391

    // workspace layout
    char* ws = (char*)d_ws;
    int* cursor  = (int*)ws;                      // nbuck          (2 KB slot)
    int* bbase   = (int*)(ws + 2048);             // nbuck          (2 KB slot)
    int* dsts    = (int*)(ws + 4096);             // nbuck*PCAP = 9.61 MB
    size_t o_rp  = 4096 + (size_t)nbuck * PCAP * 4;
    int* row_ptr = (int*)(ws + o_rp);             // n_nodes+1
    int* csr_src = (int*)(ws + o_rp + 400128);    // n_edges

    k_init<<<1, 512, 0, stream>>>(cursor, nbuck);
    k_part<<<(n_edges + PT * PEPT - 1) / (PT * PEPT), PT, 0, stream>>>(
        ei, cursor, dsts, n_edges, nbuck);
    k_bscan<<<1, 512, 0, stream>>>(cursor, bbase, row_ptr, nbuck, n_edges, n_nodes);
    k_bsort<<<nbuck, ST, 0, stream>>>(dsts, cursor, bbase, csr_src, row_ptr, n_nodes);
    k_gather_mlp<<<1024, 1024, 0, stream>>>(
        (const float4*)x, row_ptr, csr_src, eps, W1, b1, W2, b2, out, n_nodes);
}

// Round 5
// 201.320 us; speedup vs baseline: 7.6322x; 1.0790x over previous
//
#include <hip/hip_runtime.h>
#include <hip/hip_bf16.h>

// GIN conv: out = MLP((1+eps)*x + segment_sum(x[src], dst))
// N_NODES=100000, N_EDGES=1600000, NFEAT=NHID=64, NCLASS=16, fp32.
//
// Round 5: gather rework — 4 nodes per wave (lane = node q x float4 slot f):
// no cross-lane reduction, 16 independent gathers in flight per lane,
// MLP batched over 4 nodes with broadcast LDS reads, coalesced output.
// CSR build (bucket counting-sort) unchanged from R4.

#define NFEAT 64
#define NHID 64
#define NCLASS 16

#define PCAP 6144
#define MAXBUCK 512
#define PT 512
#define PEPT 8
#define ST 1024
#define SEPT 6

// ---- k0: init bucket cursors ----
__global__ __launch_bounds__(512) void k_init(int* __restrict__ cursor, int nbuck)
{
    int t = threadIdx.x;
    if (t < nbuck) cursor[t] = t * PCAP;
}

// ---- k1: partition edges into buckets by dst>>8, packed (src<<8)|(dst&255) ----
__global__ __launch_bounds__(PT) void k_part(
    const int* __restrict__ ei, int* __restrict__ cursor,
    int* __restrict__ dsts, int n_edges, int nbuck)
{
    __shared__ int lcnt[MAXBUCK];
    __shared__ int sbase[MAXBUCK];
    int tid = threadIdx.x;
    for (int i = tid; i < nbuck; i += PT) lcnt[i] = 0;
    __syncthreads();

    int e0 = blockIdx.x * (PT * PEPT);
    int bk[PEPT], rk[PEPT], pk[PEPT];
    #pragma unroll
    for (int k = 0; k < PEPT; ++k) {
        int e = e0 + k * PT + tid;
        if (e < n_edges) {
            int src = ei[e];
            int dst = ei[n_edges + e];
            int b = dst >> 8;
            bk[k] = b;
            pk[k] = (src << 8) | (dst & 255);
            rk[k] = atomicAdd(&lcnt[b], 1);
        } else bk[k] = -1;
    }
    __syncthreads();
    for (int i = tid; i < nbuck; i += PT)
        sbase[i] = lcnt[i] ? atomicAdd(&cursor[i], lcnt[i]) : 0;
    __syncthreads();
    #pragma unroll
    for (int k = 0; k < PEPT; ++k)
        if (bk[k] >= 0) dsts[sbase[bk[k]] + rk[k]] = pk[k];
}

// ---- k2: scan bucket sizes -> bucket bases ----
__global__ __launch_bounds__(512) void k_bscan(
    const int* __restrict__ cursor, int* __restrict__ bbase,
    int* __restrict__ row_ptr, int nbuck, int n_edges, int n_nodes)
{
    __shared__ int sw[8];
    int t = threadIdx.x, lane = t & 63, wid = t >> 6;
    int v = (t < nbuck) ? (cursor[t] - t * PCAP) : 0;
    int s = v;
    #pragma unroll
    for (int off = 1; off < 64; off <<= 1) {
        int u = __shfl_up(s, off);
        if (lane >= off) s += u;
    }
    if (lane == 63) sw[wid] = s;
    __syncthreads();
    if (t == 0) { int a = 0; for (int i = 0; i < 8; ++i) { int tmp = sw[i]; sw[i] = a; a += tmp; } }
    __syncthreads();
    if (t < nbuck) bbase[t] = (s - v) + sw[wid];
    if (t == 0) row_ptr[n_nodes] = n_edges;
}

// ---- k3: per-bucket counting sort -> csr_src + row_ptr ----
__global__ __launch_bounds__(ST) void k_bsort(
    const int* __restrict__ dsts, const int* __restrict__ cursor,
    const int* __restrict__ bbase, int* __restrict__ csr_src,
    int* __restrict__ row_ptr, int n_nodes)
{
    __shared__ int cnt[256];
    __shared__ int off[256];
    int b = blockIdx.x;
    int tid = threadIdx.x, lane = tid & 63, wid = tid >> 6;
    int s = cursor[b] - b * PCAP;
    int gin = b * PCAP;
    if (tid < 256) cnt[tid] = 0;
    __syncthreads();

    int dk[SEPT], rk[SEPT], sk[SEPT];
    #pragma unroll
    for (int k = 0; k < SEPT; ++k) {
        int i = k * ST + tid;
        if (i < s) {
            int p = dsts[gin + i];
            int d = p & 255;
            dk[k] = d;
            sk[k] = p >> 8;
            rk[k] = atomicAdd(&cnt[d], 1);
        } else dk[k] = -1;
    }
    __syncthreads();
    if (wid == 0) {
        int c0 = cnt[lane * 4], c1 = cnt[lane * 4 + 1], c2 = cnt[lane * 4 + 2], c3 = cnt[lane * 4 + 3];
        int p1 = c0, p2 = p1 + c1, p3 = p2 + c2, p4 = p3 + c3;
        int ss = p4;
        #pragma unroll
        for (int o = 1; o < 64; o <<= 1) {
            int u = __shfl_up(ss, o);
            if (lane >= o) ss += u;
        }
        int base = ss - p4;
        off[lane * 4] = base; off[lane * 4 + 1] = base + p1;
        off[lane * 4 + 2] = base + p2; off[lane * 4 + 3] = base + p3;
    }
    __syncthreads();
    int bb = bbase[b];
    #pragma unroll
    for (int k = 0; k < SEPT; ++k)
        if (dk[k] >= 0) csr_src[bb + off[dk[k]] + rk[k]] = sk[k];
    int node = b * 256 + tid;
    if (tid < 256 && node < n_nodes) row_ptr[node] = bb + off[tid];
}

// ---- k4: fused gather + MLP, 4 nodes per wave ----
__global__ __launch_bounds__(512) void k_gather_mlp(
    const float4* __restrict__ x4,     // [n][16]
    const int* __restrict__ row_ptr,
    const int* __restrict__ csr_src,
    const float* __restrict__ eps_p,
    const float* __restrict__ W1,
    const float* __restrict__ b1,
    const float* __restrict__ W2,
    const float* __restrict__ b2,
    float* __restrict__ out,
    int n_nodes)
{
    __shared__ float sW1[NFEAT * NHID];   // [k][j] 16 KB
    __shared__ float sW2[NHID * 17];      // [j][c] padded
    __shared__ float sb1[NHID];
    __shared__ float sb2[NCLASS];
    __shared__ float sh0[32][68];         // 32 nodes/block, padded rows
    __shared__ float sh1[32][68];
    __shared__ int   sIdx[8][64];

    int tid = threadIdx.x;
    for (int i = tid; i < NFEAT * NHID; i += 512) sW1[i] = W1[i];
    for (int i = tid; i < NHID * NCLASS; i += 512) sW2[(i >> 4) * 17 + (i & 15)] = W2[i];
    if (tid < NHID) sb1[tid] = b1[tid];
    if (tid < NCLASS) sb2[tid] = b2[tid];
    __syncthreads();

    float eps1 = 1.0f + eps_p[0];
    int wave = tid >> 6;
    int lane = tid & 63;
    int q = lane >> 4;        // node sub-index 0..3
    int f = lane & 15;        // float4 slot 0..15
    int nloc = wave * 4 + q;  // local node row

    for (int nb0 = blockIdx.x * 32; nb0 < n_nodes; nb0 += gridDim.x * 32) {
        int myNode = nb0 + nloc;
        bool valid = myNode < n_nodes;
        int s = 0, e = 0;
        if (valid) { s = row_ptr[myNode]; e = row_ptr[myNode + 1]; }
        int dmax = e - s;
        dmax = max(dmax, __shfl_xor(dmax, 16));
        dmax = max(dmax, __shfl_xor(dmax, 32));

        float4 acc = make_float4(0.f, 0.f, 0.f, 0.f);
        for (int base = 0; base < dmax; base += 16) {
            int p = s + base + f;                       // lane stages slot q*16+f
            sIdx[wave][lane] = (p < e) ? csr_src[p] : -1;
            // wave-lockstep LDS write->read, no barrier
            #pragma unroll
            for (int t = 0; t < 16; ++t) {
                int idx = sIdx[wave][q * 16 + t];
                if (idx >= 0) {
                    float4 v = x4[(size_t)idx * 16 + f];
                    acc.x += v.x; acc.y += v.y; acc.z += v.z; acc.w += v.w;
                }
            }
        }
        if (valid) {
            float4 xs = x4[(size_t)myNode * 16 + f];
            acc.x += eps1 * xs.x; acc.y += eps1 * xs.y;
            acc.z += eps1 * xs.z; acc.w += eps1 * xs.w;
        }
        *(float4*)&sh0[nloc][f * 4] = acc;

        // layer1: lane j computes h1[j] for the wave's 4 nodes
        int r = wave * 4;
        float a0 = sb1[lane], a1 = a0, a2 = a0, a3 = a0;
        #pragma unroll
        for (int kk = 0; kk < 16; ++kk) {
            float4 h0 = *(const float4*)&sh0[r + 0][kk * 4];   // broadcast reads
            float4 h1v = *(const float4*)&sh0[r + 1][kk * 4];
            float4 h2 = *(const float4*)&sh0[r + 2][kk * 4];
            float4 h3 = *(const float4*)&sh0[r + 3][kk * 4];
            #pragma unroll
            for (int i = 0; i < 4; ++i) {
                float w = sW1[(kk * 4 + i) * NHID + lane];
                a0 += ((const float*)&h0)[i] * w;
                a1 += ((const float*)&h1v)[i] * w;
                a2 += ((const float*)&h2)[i] * w;
                a3 += ((const float*)&h3)[i] * w;
            }
        }
        sh1[r + 0][lane] = fmaxf(a0, 0.f);
        sh1[r + 1][lane] = fmaxf(a1, 0.f);
        sh1[r + 2][lane] = fmaxf(a2, 0.f);
        sh1[r + 3][lane] = fmaxf(a3, 0.f);

        // layer2: lane (q,f) -> out[myNode][f]
        float o = sb2[f];
        #pragma unroll
        for (int jj = 0; jj < 16; ++jj) {
            float4 hv = *(const float4*)&sh1[nloc][jj * 4];
            o += hv.x * sW2[(jj * 4 + 0) * 17 + f];
            o += hv.y * sW2[(jj * 4 + 1) * 17 + f];
            o += hv.z * sW2[(jj * 4 + 2) * 17 + f];
            o += hv.w * sW2[(jj * 4 + 3) * 17 + f];
        }
        if (valid) out[(size_t)myNode * NCLASS + f] = o;
    }
}

extern "C" void kernel_launch(void* const* d_in, const int* in_sizes, int n_in,
                              void* d_out, int out_size, void* d_ws, size_t ws_size,
                              hipStream_t stream) {
    const float* x   = (const float*)d_in[0];
    const int*   ei  = (const int*)d_in[1];
    const float* eps = (const float*)d_in[2];
    const float* W1  = (const float*)d_in[3];
    const float* b1  = (const float*)d_in[4];
    const float* W2  = (const float*)d_in[5];
    const float* b2  = (const float*)d_in[6];
    float* out = (float*)d_out;

    int n_nodes = in_sizes[0] / NFEAT;            // 100000
    int n_edges = in_sizes[1] / 2;                // 1600000
    int nbuck = (n_nodes + 255) / 256;            // 391

    char* ws = (char*)d_ws;
    int* cursor  = (int*)ws;
    int* bbase   = (int*)(ws + 2048);
    int* dsts    = (int*)(ws + 4096);
    size_t o_rp  = 4096 + (size_t)nbuck * PCAP * 4;
    int* row_ptr = (int*)(ws + o_rp);
    int* csr_src = (int*)(ws + o_rp + 400128);

    k_init<<<1, 512, 0, stream>>>(cursor, nbuck);
    k_part<<<(n_edges + PT * PEPT - 1) / (PT * PEPT), PT, 0, stream>>>(
        ei, cursor, dsts, n_edges, nbuck);
    k_bscan<<<1, 512, 0, stream>>>(cursor, bbase, row_ptr, nbuck, n_edges, n_nodes);
    k_bsort<<<nbuck, ST, 0, stream>>>(dsts, cursor, bbase, csr_src, row_ptr, n_nodes);
    k_gather_mlp<<<(n_nodes + 31) / 32, 512, 0, stream>>>(
        (const float4*)x, row_ptr, csr_src, eps, W1, b1, W2, b2, out, n_nodes);
}